// Round 7
// baseline (48.753 us; speedup 1.0000x reference)
//
#include <hip/hip_runtime.h>
#include <hip/hip_bf16.h>

#define B_ 32
#define L_ 2048
#define E_ 256
#define H_ 256
#define MAXSTEP 20
#define NL 4      // l-tiles per block (2 half-K tiles each)
#define NCHUNK 26 // ceil(103/NL)

typedef __attribute__((ext_vector_type(4))) float f32x4;
typedef __attribute__((ext_vector_type(8))) short bf16x8;
using bf16 = __hip_bfloat16;

__device__ inline short cvt1(float x) {
    bf16 b = __float2bfloat16(x);
    return *reinterpret_cast<short*>(&b);
}

// Transpose + convert: cnn fp32 [s][e][h] -> wt bf16 [s][h][e] (K-contiguous B operand).
__global__ void transpose_w_kernel(const float* __restrict__ cnn, short* __restrict__ wt) {
    __shared__ short tile[32][33];
    const int s  = blockIdx.z;
    const int e0 = blockIdx.y * 32;
    const int h0 = blockIdx.x * 32;
    const int tx = threadIdx.x;
    const int ty = threadIdx.y;
    const float* src = cnn + ((size_t)s * E_ + e0) * H_ + h0;
#pragma unroll
    for (int i = ty; i < 32; i += 8)
        tile[i][tx] = cvt1(src[(size_t)i * H_ + tx]);
    __syncthreads();
    short* dst = wt + ((size_t)s * H_ + h0) * E_ + e0;
#pragma unroll
    for (int i = ty; i < 32; i += 8)
        dst[(size_t)i * E_ + tx] = tile[tx][i];
}

// Same-s blocking; half-K pipeline. Block = (s, chunk); handles NL l's, each as
// 2 half-K tiles (32 rows x 128 k, 16 KB). 3 LDS buffers (48 KB) -> 3 blocks/CU;
// stage runs 2 tiles ahead so ~32 KB/block is perpetually in flight. B (W^T[s],
// this wave's 64 h-rows, full K) lives in 128 VGPRs (L2-resident load, once).
// In-order vmcnt queue at the wait of tile t (stage=4 ops, stores=32 ops):
//   t=0: [s0:4|s1:4|s2:4]                 -> vmcnt(8) retires s0
//   t=1: [s1:4|s2:4|s3:4]                 -> vmcnt(8)
//   2<=t<6: [..s(t):4|{ST:32,s(t+1):4}|s(t+2):4] -> newest 40 exclude s(t) -> vmcnt(40)
//   t=6: [s6:4|s7:4|ST:32]                -> vmcnt(36);  t=7: [s7:4|ST:32] -> vmcnt(32)
// mfma_f32_16x16x32_bf16: A row=lane&15, k=(lane>>4)*8+j; B col=lane&15;
// C/D col=lane&15, row=(lane>>4)*4+reg.
__global__ __launch_bounds__(256, 2) void vaw_sames_kernel(
        const float* __restrict__ A, const short* __restrict__ Wt,
        float* __restrict__ out) {
    __shared__ __align__(16) float aLds[3][B_ * 128];   // 3 x 16 KB

    const int s     = blockIdx.x / NCHUNK;
    const int chunk = blockIdx.x % NCHUNK;
    const int cnt   = (s < 8) ? 103 : 102;   // #{l < 2048 : l % 20 == s}
    const int wv    = threadIdx.x >> 6;
    const int lane  = threadIdx.x & 63;
    const int r     = lane & 15;
    const int g     = lane >> 4;
    const int nbase = wv * 64;
    const int key   = r & 7;                 // (r+16)&7 == r&7

    // ---- B into registers: breg[kk][nf], 32 x 16B loads from L2-resident Wt.
    const short* wtb = Wt + ((size_t)s * H_ + nbase + r) * E_ + g * 8;
    bf16x8 breg[8][4];
#pragma unroll
    for (int kk = 0; kk < 8; ++kk)
#pragma unroll
        for (int nf = 0; nf < 4; ++nf)
            breg[kk][nf] = *(const bf16x8*)(wtb + (size_t)nf * 16 * E_ + kk * 32);

    auto lof = [&](int il) {
        int idx = chunk * NL + il;
        if (idx > cnt - 1) idx = cnt - 1;    // tail clamp: duplicate work, benign
        return s + 20 * idx;
    };

    // Stage half-tile t into aLds[t%3]. Each instr moves 1 KB = 2 rows of 128
    // floats; wave wv stages rows {j*8+wv*2, +1}, j=0..3. Global source chunk
    // XOR-swizzled per row (LDS dest linear, as global_load_lds requires).
    auto stage = [&](int t) {
        const int l  = lof(t >> 1);
        const int hk = t & 1;
        float* dst = aLds[t % 3];
        const int local = lane & 31;
        const int half  = lane >> 5;
#pragma unroll
        for (int j = 0; j < 4; ++j) {
            const int r0  = j * 8 + wv * 2;
            const int row = r0 + half;
            const int cg  = local ^ (row & 7);
            const float* gp = A + ((size_t)row * L_ + l) * E_ + hk * 128 + cg * 4;
            __builtin_amdgcn_global_load_lds(
                (const __attribute__((address_space(1))) void*)gp,
                (__attribute__((address_space(3))) void*)&dst[r0 * 128],
                16, 0, 0);
        }
    };

    stage(0);
    stage(1);

    f32x4 acc[2][4];

#pragma unroll
    for (int t = 0; t < 2 * NL; ++t) {
        const int cur = t % 3;
        const int hk  = t & 1;
        const int l   = lof(t >> 1);

        if (t < 2 * NL - 2) stage(t + 2);

        if (t < 2)                asm volatile("s_waitcnt vmcnt(8)"  ::: "memory");
        else if (t < 2 * NL - 2)  asm volatile("s_waitcnt vmcnt(40)" ::: "memory");
        else if (t == 2 * NL - 2) asm volatile("s_waitcnt vmcnt(36)" ::: "memory");
        else                      asm volatile("s_waitcnt vmcnt(32)" ::: "memory");
        __builtin_amdgcn_s_barrier();        // all waves' stage(t) landed
        __builtin_amdgcn_sched_barrier(0);

        if (hk == 0) {
#pragma unroll
            for (int mf = 0; mf < 2; ++mf)
#pragma unroll
                for (int nf = 0; nf < 4; ++nf)
                    acc[mf][nf] = f32x4{0.f, 0.f, 0.f, 0.f};
        }

#pragma unroll
        for (int kkh = 0; kkh < 4; ++kkh) {
            const int kk = hk * 4 + kkh;
            const int c0 = kkh * 8 + g * 2;
            f32x4 a0lo = *(const f32x4*)&aLds[cur][r * 128 + ((c0 ^ key) << 2)];
            f32x4 a0hi = *(const f32x4*)&aLds[cur][r * 128 + (((c0 + 1) ^ key) << 2)];
            f32x4 a1lo = *(const f32x4*)&aLds[cur][(r + 16) * 128 + ((c0 ^ key) << 2)];
            f32x4 a1hi = *(const f32x4*)&aLds[cur][(r + 16) * 128 + (((c0 + 1) ^ key) << 2)];
            bf16x8 a0, a1;
#pragma unroll
            for (int j = 0; j < 4; ++j) {
                a0[j]     = cvt1(a0lo[j]);
                a0[j + 4] = cvt1(a0hi[j]);
                a1[j]     = cvt1(a1lo[j]);
                a1[j + 4] = cvt1(a1hi[j]);
            }
#pragma unroll
            for (int nf = 0; nf < 4; ++nf) {
                acc[0][nf] = __builtin_amdgcn_mfma_f32_16x16x32_bf16(a0, breg[kk][nf], acc[0][nf], 0, 0, 0);
                acc[1][nf] = __builtin_amdgcn_mfma_f32_16x16x32_bf16(a1, breg[kk][nf], acc[1][nf], 0, 0, 0);
            }
        }

        if (hk == 1) {
            const int row0 = g * 4;
#pragma unroll
            for (int mf = 0; mf < 2; ++mf) {
#pragma unroll
                for (int nf = 0; nf < 4; ++nf) {
                    const int h = nbase + nf * 16 + r;
#pragma unroll
                    for (int i = 0; i < 4; ++i) {
                        const int bb = mf * 16 + row0 + i;
                        out[((size_t)bb * L_ + l) * H_ + h] = acc[mf][nf][i];
                    }
                }
            }
            if (l == L_ - 1) {
                float* out2 = out + (size_t)B_ * L_ * H_;
#pragma unroll
                for (int mf = 0; mf < 2; ++mf)
#pragma unroll
                    for (int nf = 0; nf < 4; ++nf) {
                        const int h = nbase + nf * 16 + r;
#pragma unroll
                        for (int i = 0; i < 4; ++i) {
                            const int bb = mf * 16 + row0 + i;
                            out2[(size_t)bb * H_ + h] = acc[mf][nf][i];
                        }
                    }
            }
        }

        __builtin_amdgcn_s_barrier();   // reads of buf[cur] done before reuse
    }
}

// Fallback (no workspace): round-5 structure, B from fp32 cnn per k-step.
__global__ __launch_bounds__(256) void vaw_fallback_kernel(
        const float* __restrict__ A, const float* __restrict__ W, float* __restrict__ out) {
    __shared__ __align__(16) float aLds[2][B_ * E_];
    const int l0   = blockIdx.x * NL;
    const int wv   = threadIdx.x >> 6;
    const int lane = threadIdx.x & 63;
    const int r    = lane & 15;
    const int g    = lane >> 4;
    const int nbase = wv * 64;
    const int key   = r & 7;

    auto stage = [&](int it) {
        float* dst = aLds[it & 1];
        const int l = l0 + it;
#pragma unroll
        for (int t = 0; t < 8; ++t) {
            const int b  = t * 4 + wv;
            const int cg = lane ^ (b & 7);
            const float* gp = A + ((size_t)b * L_ + l) * E_ + cg * 4;
            __builtin_amdgcn_global_load_lds(
                (const __attribute__((address_space(1))) void*)gp,
                (__attribute__((address_space(3))) void*)&dst[b * 256],
                16, 0, 0);
        }
    };

    stage(0);
#pragma unroll 1
    for (int it = 0; it < NL; ++it) {
        const int l   = l0 + it;
        const int sidx = l % MAXSTEP;
        const int cur = it & 1;
        if (it < NL - 1) {
            stage(it + 1);
            asm volatile("s_waitcnt vmcnt(8)" ::: "memory");
        } else {
            asm volatile("s_waitcnt vmcnt(0)" ::: "memory");
        }
        __builtin_amdgcn_s_barrier();
        __builtin_amdgcn_sched_barrier(0);

        f32x4 acc[2][4] = {};
        const float* Wf = W + (size_t)sidx * E_ * H_;
#pragma unroll 2
        for (int kk = 0; kk < 8; ++kk) {
            const int k0 = kk * 32;
            const int c0 = kk * 8 + g * 2;
            f32x4 a0lo = *(const f32x4*)&aLds[cur][r * 256 + ((c0 ^ key) << 2)];
            f32x4 a0hi = *(const f32x4*)&aLds[cur][r * 256 + (((c0 + 1) ^ key) << 2)];
            f32x4 a1lo = *(const f32x4*)&aLds[cur][(r + 16) * 256 + ((c0 ^ key) << 2)];
            f32x4 a1hi = *(const f32x4*)&aLds[cur][(r + 16) * 256 + (((c0 + 1) ^ key) << 2)];
            bf16x8 a0, a1;
#pragma unroll
            for (int j = 0; j < 4; ++j) {
                a0[j]     = cvt1(a0lo[j]);
                a0[j + 4] = cvt1(a0hi[j]);
                a1[j]     = cvt1(a1lo[j]);
                a1[j + 4] = cvt1(a1hi[j]);
            }
            bf16x8 b0, b1, b2, b3;
#pragma unroll
            for (int j = 0; j < 8; ++j) {
                const size_t krow = (size_t)(k0 + g * 8 + j) * H_;
                b0[j] = cvt1(Wf[krow + nbase +  0 + r]);
                b1[j] = cvt1(Wf[krow + nbase + 16 + r]);
                b2[j] = cvt1(Wf[krow + nbase + 32 + r]);
                b3[j] = cvt1(Wf[krow + nbase + 48 + r]);
            }
            acc[0][0] = __builtin_amdgcn_mfma_f32_16x16x32_bf16(a0, b0, acc[0][0], 0, 0, 0);
            acc[0][1] = __builtin_amdgcn_mfma_f32_16x16x32_bf16(a0, b1, acc[0][1], 0, 0, 0);
            acc[0][2] = __builtin_amdgcn_mfma_f32_16x16x32_bf16(a0, b2, acc[0][2], 0, 0, 0);
            acc[0][3] = __builtin_amdgcn_mfma_f32_16x16x32_bf16(a0, b3, acc[0][3], 0, 0, 0);
            acc[1][0] = __builtin_amdgcn_mfma_f32_16x16x32_bf16(a1, b0, acc[1][0], 0, 0, 0);
            acc[1][1] = __builtin_amdgcn_mfma_f32_16x16x32_bf16(a1, b1, acc[1][1], 0, 0, 0);
            acc[1][2] = __builtin_amdgcn_mfma_f32_16x16x32_bf16(a1, b2, acc[1][2], 0, 0, 0);
            acc[1][3] = __builtin_amdgcn_mfma_f32_16x16x32_bf16(a1, b3, acc[1][3], 0, 0, 0);
        }

        const int row0 = g * 4;
#pragma unroll
        for (int mf = 0; mf < 2; ++mf)
#pragma unroll
            for (int nf = 0; nf < 4; ++nf) {
                const int h = nbase + nf * 16 + r;
#pragma unroll
                for (int i = 0; i < 4; ++i) {
                    const int bb = mf * 16 + row0 + i;
                    out[((size_t)bb * L_ + l) * H_ + h] = acc[mf][nf][i];
                }
            }
        if (l == L_ - 1) {
            float* out2 = out + (size_t)B_ * L_ * H_;
#pragma unroll
            for (int mf = 0; mf < 2; ++mf)
#pragma unroll
                for (int nf = 0; nf < 4; ++nf) {
                    const int h = nbase + nf * 16 + r;
#pragma unroll
                    for (int i = 0; i < 4; ++i) {
                        const int bb = mf * 16 + row0 + i;
                        out2[(size_t)bb * H_ + h] = acc[mf][nf][i];
                    }
                }
        }
        __builtin_amdgcn_s_barrier();
    }
}

extern "C" void kernel_launch(void* const* d_in, const int* in_sizes, int n_in,
                              void* d_out, int out_size, void* d_ws, size_t ws_size,
                              hipStream_t stream) {
    const float* word_rep = (const float*)d_in[0];
    const float* cnn      = (const float*)d_in[1];
    float* out = (float*)d_out;

    const size_t wt_bytes = (size_t)MAXSTEP * E_ * H_ * sizeof(short);
    if (ws_size >= wt_bytes) {
        short* wt = (short*)d_ws;
        transpose_w_kernel<<<dim3(8, 8, 20), dim3(32, 8), 0, stream>>>(cnn, wt);
        vaw_sames_kernel<<<dim3(MAXSTEP * NCHUNK), dim3(256), 0, stream>>>(word_rep, wt, out);
    } else {
        vaw_fallback_kernel<<<dim3(L_ / NL), dim3(256), 0, stream>>>(word_rep, cnn, out);
    }
}